// Round 5
// baseline (60237.323 us; speedup 1.0000x reference)
//
#include <hip/hip_runtime.h>

#define BATCH 64
#define NH 224          // rows of img2d (and eigen dimension)
#define NCW 672         // cols of img2d
#define CSTRIDE 256     // padded column stride for G (224 data + 32 zero pad)
#define KKEEP 179       // int(0.8*224)
#define NTAIL 45        // 224 - 179
#define NSWEEPS 10
#define EPS2 1e-18f

__device__ __forceinline__ float fast_rcp(float x) { return __builtin_amdgcn_rcpf(x); }
__device__ __forceinline__ float fast_rsq(float x) { return __builtin_amdgcn_rsqf(x); }
__device__ __forceinline__ float fast_sqrt(float x) { return __builtin_amdgcn_sqrtf(x); }

// Intra-block disjoint pair schedule: 7 mini-rounds x 3 pairs, i+j == t (mod 7)
// constexpr so full unroll folds all indexing to immediates (no memory access).
constexpr int IP[7][3][2] = {
    {{1, 6}, {2, 5}, {3, 4}},
    {{0, 1}, {2, 6}, {3, 5}},
    {{0, 2}, {3, 6}, {4, 5}},
    {{0, 3}, {1, 2}, {4, 6}},
    {{0, 4}, {1, 3}, {5, 6}},
    {{0, 5}, {1, 4}, {2, 3}},
    {{0, 6}, {1, 5}, {2, 4}}};

// Unconditional (select-guarded) Jacobi rotation given the reduced dot apq.
// tt==0 -> identity rotation; no branches, no extra live temps.
__device__ __forceinline__ void apply_rot(float4& A, float4& B, float& LA,
                                          float& LB, float apq) {
    float tau = (LB - LA) * 0.5f * fast_rcp(apq);
    float tt = copysignf(fast_rcp(fabsf(tau) + fast_sqrt(1.f + tau * tau)), tau);
    tt = (apq * apq > EPS2 * LA * LB) ? tt : 0.f;
    float cc = fast_rsq(1.f + tt * tt);
    float ss = tt * cc;
    float ax = A.x, ay = A.y, az = A.z, aw = A.w;
    A.x = cc * ax - ss * B.x; B.x = ss * ax + cc * B.x;
    A.y = cc * ay - ss * B.y; B.y = ss * ay + cc * B.y;
    A.z = cc * az - ss * B.z; B.z = ss * az + cc * B.z;
    A.w = cc * aw - ss * B.w; B.w = ss * aw + cc * B.w;
    LA -= tt * apq; LB += tt * apq;
}

// ---------------------------------------------------------------- p_obs
__global__ __launch_bounds__(256) void pobs_kernel(const int* __restrict__ mask,
                                                   float* __restrict__ invp) {
    int b = blockIdx.x, tid = threadIdx.x;
    const int* mb = mask + (size_t)b * NH * NCW;
    int s = 0;
    for (int i = tid; i < NH * NCW; i += 256) s += mb[i];
    __shared__ int red[256];
    red[tid] = s;
    __syncthreads();
    for (int o = 128; o; o >>= 1) {
        if (tid < o) red[tid] += red[tid + o];
        __syncthreads();
    }
    if (tid == 0) invp[b] = (float)(NH * NCW) / (float)red[0];
}

// ------------------------------------------------- zero the pad rows of G
__global__ void pad_kernel(float* __restrict__ G) {
    int idx = blockIdx.x * 256 + threadIdx.x;  // BATCH*224*32 total
    int b = idx / (NH * 32);
    int rem = idx - b * (NH * 32);
    int j = rem >> 5;
    int i = NH + (rem & 31);
    G[((size_t)b * NH + j) * CSTRIDE + i] = 0.f;
}

// ------------------------------------------------------- G = A * A^T
__global__ __launch_bounds__(256) void gram_kernel(const float* __restrict__ x,
                                                   const int* __restrict__ mask,
                                                   float* __restrict__ G) {
    int b = blockIdx.y;
    int tile = blockIdx.x;       // 0..48
    int ti = tile / 7, tj = tile - ti * 7;
    int i0 = ti * 32, j0 = tj * 32;
    __shared__ float As[32][33];
    __shared__ float Bs[32][33];
    int tid = threadIdx.x;
    int tx = tid & 31;
    int ty = tid >> 5;
    float acc0 = 0, acc1 = 0, acc2 = 0, acc3 = 0;
    const float* xb = x + (size_t)b * 3 * NH * NH;
    const int* mb = mask + (size_t)b * NH * NCW;
    for (int ks = 0; ks < 21; ++ks) {
        int k0 = ks * 32;
        int c = k0 / NH;
        int w0 = k0 - c * NH;
        __syncthreads();
        for (int l = tid; l < 1024; l += 256) {
            int dk = l & 31, di = l >> 5;
            int hA = i0 + di, hB = j0 + di;
            float xa = xb[(c * NH + hA) * NH + w0 + dk];
            float xc = xb[(c * NH + hB) * NH + w0 + dk];
            As[di][dk] = mb[hA * NCW + k0 + dk] ? 2.f * xa - 1.f : 0.f;
            Bs[di][dk] = mb[hB * NCW + k0 + dk] ? 2.f * xc - 1.f : 0.f;
        }
        __syncthreads();
#pragma unroll
        for (int kk = 0; kk < 32; ++kk) {
            float bv = Bs[tx][kk];
            acc0 += As[ty][kk] * bv;
            acc1 += As[ty + 8][kk] * bv;
            acc2 += As[ty + 16][kk] * bv;
            acc3 += As[ty + 24][kk] * bv;
        }
    }
    float* Gb = G + (size_t)b * NH * CSTRIDE;
    int j = j0 + tx;
    Gb[j * CSTRIDE + i0 + ty] = acc0;
    Gb[j * CSTRIDE + i0 + ty + 8] = acc1;
    Gb[j * CSTRIDE + i0 + ty + 16] = acc2;
    Gb[j * CSTRIDE + i0 + ty + 24] = acc3;
}

// ---------------------------------------------- blocked one-sided Jacobi
// 32 blocks x 7 columns; tournament over block pairs, one wave per pair.
// Mini-rounds of disjoint pairs: dots computed together, 6-level shuffle
// trees interleaved (amortize ds-op latency), then unconditional updates.
__global__ __launch_bounds__(1024, 4) void jacobi_kernel(float* __restrict__ G) {
    int b = blockIdx.x;
    float* Gb = G + (size_t)b * NH * CSTRIDE;
    __shared__ float lam[NH];
    int tid = threadIdx.x, lane = tid & 63, wid = tid >> 6;  // 16 waves
    for (int k = 0; k < 14; ++k) {
        int j = wid * 14 + k;
        float4 v = ((const float4*)(Gb + j * CSTRIDE))[lane];
        float d = v.x * v.x + v.y * v.y + v.z * v.z + v.w * v.w;
        d += __shfl_xor(d, 32); d += __shfl_xor(d, 16); d += __shfl_xor(d, 8);
        d += __shfl_xor(d, 4);  d += __shfl_xor(d, 2);  d += __shfl_xor(d, 1);
        if (lane == 0) lam[j] = d;
    }
    __syncthreads();
    for (int sweep = 0; sweep < NSWEEPS; ++sweep) {
        for (int r = 0; r < 31; ++r) {
            int bp, bq;
            if (wid == 0) {
                bp = 31; bq = r;
            } else {
                bp = r + wid; if (bp >= 31) bp -= 31;
                bq = r - wid; if (bq < 0) bq += 31;
            }
            // hoisted bases: element k of block p at bpp[k*64] (k*1024B imm)
            float4* bpp = (float4*)Gb + bp * 7 * 64 + lane;
            float4* bqq = (float4*)Gb + bq * 7 * 64 + lane;
            float4 c[14];
            float l[14];
#pragma unroll
            for (int k = 0; k < 7; ++k) {
                c[k]     = bpp[k * 64];
                c[7 + k] = bqq[k * 64];
                l[k]     = lam[bp * 7 + k];
                l[7 + k] = lam[bq * 7 + k];
            }
            if (r == 0) {
                // intra-block: 7 mini-rounds x 6 disjoint pairs (3 per block)
#pragma unroll
                for (int t = 0; t < 7; ++t) {
                    float apq[6];
#pragma unroll
                    for (int k = 0; k < 6; ++k) {
                        int p = IP[t][k % 3][0] + (k < 3 ? 0 : 7);
                        int q = IP[t][k % 3][1] + (k < 3 ? 0 : 7);
                        apq[k] = c[p].x * c[q].x + c[p].y * c[q].y +
                                 c[p].z * c[q].z + c[p].w * c[q].w;
                    }
#pragma unroll
                    for (int o = 32; o; o >>= 1)
#pragma unroll
                        for (int k = 0; k < 6; ++k) apq[k] += __shfl_xor(apq[k], o);
#pragma unroll
                    for (int k = 0; k < 6; ++k) {
                        int p = IP[t][k % 3][0] + (k < 3 ? 0 : 7);
                        int q = IP[t][k % 3][1] + (k < 3 ? 0 : 7);
                        apply_rot(c[p], c[q], l[p], l[q], apq[k]);
                    }
                }
            }
            // cross-block: 7 mini-rounds x 7 disjoint pairs
#pragma unroll
            for (int s = 0; s < 7; ++s) {
                float apq[7];
#pragma unroll
                for (int k = 0; k < 7; ++k) {
                    int q = 7 + ((k + s) % 7);
                    apq[k] = c[k].x * c[q].x + c[k].y * c[q].y +
                             c[k].z * c[q].z + c[k].w * c[q].w;
                }
#pragma unroll
                for (int o = 32; o; o >>= 1)
#pragma unroll
                    for (int k = 0; k < 7; ++k) apq[k] += __shfl_xor(apq[k], o);
#pragma unroll
                for (int k = 0; k < 7; ++k) {
                    int q = 7 + ((k + s) % 7);
                    apply_rot(c[k], c[q], l[k], l[q], apq[k]);
                }
            }
#pragma unroll
            for (int k = 0; k < 7; ++k) {
                bpp[k * 64] = c[k];
                bqq[k * 64] = c[7 + k];
                if (lane == 0) {
                    lam[bp * 7 + k] = l[k];
                    lam[bq * 7 + k] = l[7 + k];
                }
            }
            __syncthreads();
        }
    }
}

// --------------------------------- exact norms + select 45 smallest
__global__ __launch_bounds__(256) void select_kernel(const float* __restrict__ G,
                                                     int* __restrict__ tail_idx,
                                                     float* __restrict__ invl2) {
    int b = blockIdx.x;
    const float* Gb = G + (size_t)b * NH * CSTRIDE;
    __shared__ float lam[NH];
    __shared__ int cnt;
    int tid = threadIdx.x, lane = tid & 63, wid = tid >> 6;  // 4 waves
    if (tid == 0) cnt = 0;
    for (int j = wid * 56; j < wid * 56 + 56; ++j) {
        float4 v = ((const float4*)(Gb + j * CSTRIDE))[lane];
        float d = v.x * v.x + v.y * v.y + v.z * v.z + v.w * v.w;
        d += __shfl_xor(d, 32); d += __shfl_xor(d, 16); d += __shfl_xor(d, 8);
        d += __shfl_xor(d, 4);  d += __shfl_xor(d, 2);  d += __shfl_xor(d, 1);
        if (lane == 0) lam[j] = d;
    }
    __syncthreads();
    if (tid < NH) {
        float my = lam[tid];
        int rank = 0;
        for (int i = 0; i < NH; ++i) {
            float o = lam[i];
            rank += (o > my) ? 1 : ((o == my && i < tid) ? 1 : 0);
        }
        if (rank >= KKEEP) {
            int pos = atomicAdd(&cnt, 1);
            tail_idx[b * NTAIL + pos] = tid;
            invl2[b * NTAIL + pos] = 1.f / my;  // ||col||^2 = lambda^2
        }
    }
}

// ------------------------------- C[b][t][w'] = (col_t^T A)[w'] / lambda^2
__global__ __launch_bounds__(128) void ctail_kernel(const float* __restrict__ G,
                                                    const float* __restrict__ x,
                                                    const int* __restrict__ mask,
                                                    const int* __restrict__ tail_idx,
                                                    const float* __restrict__ invl2,
                                                    float* __restrict__ C) {
    int b = blockIdx.y;
    int wchunk = blockIdx.x;  // 6 chunks of 112
    __shared__ float sT[NTAIL * NH];
    __shared__ float sInv[NTAIL];
    __shared__ int sIdx[NTAIL];
    int tid = threadIdx.x;
    if (tid < NTAIL) {
        sIdx[tid] = tail_idx[b * NTAIL + tid];
        sInv[tid] = invl2[b * NTAIL + tid];
    }
    __syncthreads();
    for (int idx = tid; idx < NTAIL * NH; idx += 128) {
        int t = idx / NH, h = idx - t * NH;
        sT[idx] = G[((size_t)b * NH + sIdx[t]) * CSTRIDE + h];
    }
    __syncthreads();
    if (tid < 112) {
        int wp = wchunk * 112 + tid;
        int c = wp / NH;
        int w = wp - c * NH;
        const float* xb = x + ((size_t)(b * 3 + c) * NH) * NH + w;
        const int* mb = mask + (size_t)b * NH * NCW + wp;
        float acc[NTAIL];
#pragma unroll
        for (int t = 0; t < NTAIL; ++t) acc[t] = 0.f;
        for (int h = 0; h < NH; ++h) {
            float a = mb[h * NCW] ? 2.f * xb[h * NH] - 1.f : 0.f;
#pragma unroll
            for (int t = 0; t < NTAIL; ++t) acc[t] += sT[t * NH + h] * a;
        }
        float* Cb = C + ((size_t)b * NTAIL) * NCW + wp;
#pragma unroll
        for (int t = 0; t < NTAIL; ++t) Cb[t * NCW] = acc[t] * sInv[t];
    }
}

// ----------------------------------------------------------- final output
__global__ __launch_bounds__(256) void out_kernel(const float* __restrict__ G,
                                                  const float* __restrict__ x,
                                                  const int* __restrict__ mask,
                                                  const int* __restrict__ tail_idx,
                                                  const float* __restrict__ C,
                                                  const float* __restrict__ invp,
                                                  float* __restrict__ out) {
    int b = blockIdx.z, hc = blockIdx.y, wc = blockIdx.x;
    int h0 = hc * 32, w0 = wc * 96;
    __shared__ float sCol[NTAIL * 32];
    __shared__ float sC[NTAIL * 96];
    __shared__ int sIdx[NTAIL];
    int tid = threadIdx.x;
    if (tid < NTAIL) sIdx[tid] = tail_idx[b * NTAIL + tid];
    __syncthreads();
    for (int i = tid; i < NTAIL * 32; i += 256) {
        int t = i >> 5, hl = i & 31;
        sCol[i] = G[((size_t)b * NH + sIdx[t]) * CSTRIDE + h0 + hl];
    }
    for (int i = tid; i < NTAIL * 96; i += 256) {
        int t = i / 96, wl = i - t * 96;
        sC[i] = C[((size_t)b * NTAIL + t) * NCW + w0 + wl];
    }
    __syncthreads();
    float ip = invp[b];
    for (int i = tid; i < 32 * 96; i += 256) {
        int hl = i / 96, wl = i - hl * 96;
        int h = h0 + hl, wp = w0 + wl;
        int c = wp / NH, w = wp - c * NH;
        float a = mask[(size_t)b * NH * NCW + h * NCW + wp]
                      ? 2.f * x[((size_t)(b * 3 + c) * NH + h) * NH + w] - 1.f
                      : 0.f;
        float corr = 0.f;
#pragma unroll
        for (int t = 0; t < NTAIL; ++t) corr += sCol[t * 32 + hl] * sC[t * 96 + wl];
        float val = (a - corr) * ip;
        val = fminf(1.f, fmaxf(-1.f, val));
        out[((size_t)(b * 3 + c) * NH + h) * NH + w] = (val + 1.f) * 0.5f;
    }
}

extern "C" void kernel_launch(void* const* d_in, const int* in_sizes, int n_in,
                              void* d_out, int out_size, void* d_ws, size_t ws_size,
                              hipStream_t stream) {
    const float* x = (const float*)d_in[0];
    const int* mask = (const int*)d_in[1];
    float* out = (float*)d_out;
    char* ws = (char*)d_ws;

    const size_t off_G = 0;
    const size_t sz_G = (size_t)BATCH * NH * CSTRIDE * 4;
    const size_t off_invp = off_G + sz_G;
    const size_t off_tail = off_invp + 256;
    const size_t off_invl2 = off_tail + (size_t)BATCH * NTAIL * 4;
    const size_t off_C = off_invl2 + (size_t)BATCH * NTAIL * 4;

    float* G = (float*)(ws + off_G);
    float* invp = (float*)(ws + off_invp);
    int* tail = (int*)(ws + off_tail);
    float* invl2 = (float*)(ws + off_invl2);
    float* C = (float*)(ws + off_C);

    pobs_kernel<<<BATCH, 256, 0, stream>>>(mask, invp);
    pad_kernel<<<(BATCH * NH * 32) / 256, 256, 0, stream>>>(G);
    gram_kernel<<<dim3(49, BATCH), 256, 0, stream>>>(x, mask, G);
    jacobi_kernel<<<BATCH, 1024, 0, stream>>>(G);
    select_kernel<<<BATCH, 256, 0, stream>>>(G, tail, invl2);
    ctail_kernel<<<dim3(6, BATCH), 128, 0, stream>>>(G, x, mask, tail, invl2, C);
    out_kernel<<<dim3(7, 7, BATCH), 256, 0, stream>>>(G, x, mask, tail, C, invp, out);
}

// Round 6
// 39608.139 us; speedup vs baseline: 1.5208x; 1.5208x over previous
//
#include <hip/hip_runtime.h>

#define BATCH 64
#define NH 224          // rows of img2d (and eigen dimension)
#define NCW 672         // cols of img2d
#define CSTRIDE 256     // padded column stride for G (224 data + 32 zero pad)
#define KKEEP 179       // int(0.8*224)
#define NTAIL 45        // 224 - 179
#define NSWEEPS 10
#define EPS2 1e-18f

__device__ __forceinline__ float fast_rcp(float x) { return __builtin_amdgcn_rcpf(x); }
__device__ __forceinline__ float fast_rsq(float x) { return __builtin_amdgcn_rsqf(x); }
__device__ __forceinline__ float fast_sqrt(float x) { return __builtin_amdgcn_sqrtf(x); }

__device__ __forceinline__ float dot4(const float4& a, const float4& b) {
    return a.x * b.x + a.y * b.y + a.z * b.z + a.w * b.w;
}

// Unconditional (select-guarded) Jacobi rotation given the reduced dot apq.
__device__ __forceinline__ void apply_rot(float4& A, float4& B, float& LA,
                                          float& LB, float apq) {
    float tau = (LB - LA) * 0.5f * fast_rcp(apq);
    float tt = copysignf(fast_rcp(fabsf(tau) + fast_sqrt(1.f + tau * tau)), tau);
    tt = (apq * apq > EPS2 * LA * LB) ? tt : 0.f;
    float cc = fast_rsq(1.f + tt * tt);
    float ss = tt * cc;
    float ax = A.x, ay = A.y, az = A.z, aw = A.w;
    A.x = cc * ax - ss * B.x; B.x = ss * ax + cc * B.x;
    A.y = cc * ay - ss * B.y; B.y = ss * ay + cc * B.y;
    A.z = cc * az - ss * B.z; B.z = ss * az + cc * B.z;
    A.w = cc * aw - ss * B.w; B.w = ss * aw + cc * B.w;
    LA -= tt * apq; LB += tt * apq;
}

// ---------------------------------------------------------------- p_obs
__global__ __launch_bounds__(256) void pobs_kernel(const int* __restrict__ mask,
                                                   float* __restrict__ invp) {
    int b = blockIdx.x, tid = threadIdx.x;
    const int* mb = mask + (size_t)b * NH * NCW;
    int s = 0;
    for (int i = tid; i < NH * NCW; i += 256) s += mb[i];
    __shared__ int red[256];
    red[tid] = s;
    __syncthreads();
    for (int o = 128; o; o >>= 1) {
        if (tid < o) red[tid] += red[tid + o];
        __syncthreads();
    }
    if (tid == 0) invp[b] = (float)(NH * NCW) / (float)red[0];
}

// ------------------------------------------------- zero the pad rows of G
__global__ void pad_kernel(float* __restrict__ G) {
    int idx = blockIdx.x * 256 + threadIdx.x;  // BATCH*224*32 total
    int b = idx / (NH * 32);
    int rem = idx - b * (NH * 32);
    int j = rem >> 5;
    int i = NH + (rem & 31);
    G[((size_t)b * NH + j) * CSTRIDE + i] = 0.f;
}

// ------------------------------------------------------- G = A * A^T
__global__ __launch_bounds__(256) void gram_kernel(const float* __restrict__ x,
                                                   const int* __restrict__ mask,
                                                   float* __restrict__ G) {
    int b = blockIdx.y;
    int tile = blockIdx.x;       // 0..48
    int ti = tile / 7, tj = tile - ti * 7;
    int i0 = ti * 32, j0 = tj * 32;
    __shared__ float As[32][33];
    __shared__ float Bs[32][33];
    int tid = threadIdx.x;
    int tx = tid & 31;
    int ty = tid >> 5;
    float acc0 = 0, acc1 = 0, acc2 = 0, acc3 = 0;
    const float* xb = x + (size_t)b * 3 * NH * NH;
    const int* mb = mask + (size_t)b * NH * NCW;
    for (int ks = 0; ks < 21; ++ks) {
        int k0 = ks * 32;
        int c = k0 / NH;
        int w0 = k0 - c * NH;
        __syncthreads();
        for (int l = tid; l < 1024; l += 256) {
            int dk = l & 31, di = l >> 5;
            int hA = i0 + di, hB = j0 + di;
            float xa = xb[(c * NH + hA) * NH + w0 + dk];
            float xc = xb[(c * NH + hB) * NH + w0 + dk];
            As[di][dk] = mb[hA * NCW + k0 + dk] ? 2.f * xa - 1.f : 0.f;
            Bs[di][dk] = mb[hB * NCW + k0 + dk] ? 2.f * xc - 1.f : 0.f;
        }
        __syncthreads();
#pragma unroll
        for (int kk = 0; kk < 32; ++kk) {
            float bv = Bs[tx][kk];
            acc0 += As[ty][kk] * bv;
            acc1 += As[ty + 8][kk] * bv;
            acc2 += As[ty + 16][kk] * bv;
            acc3 += As[ty + 24][kk] * bv;
        }
    }
    float* Gb = G + (size_t)b * NH * CSTRIDE;
    int j = j0 + tx;
    Gb[j * CSTRIDE + i0 + ty] = acc0;
    Gb[j * CSTRIDE + i0 + ty + 8] = acc1;
    Gb[j * CSTRIDE + i0 + ty + 16] = acc2;
    Gb[j * CSTRIDE + i0 + ty + 24] = acc3;
}

// ---------------------------------------------- blocked one-sided Jacobi
// 16 blocks x 14 columns; tournament: 15 rounds x 8 block-pairs, one wave
// per pair, 512-thread WG (8 waves). c[28] lives in registers; the
// (512,2) launch bound allows up to 256 VGPRs (1024-thread WGs pinned the
// allocator at 64 VGPRs -> catastrophic scratch spill, R3-R5).
// Mini-rounds of 14 disjoint pairs interleave the 6-level shuffle trees.
__global__ __launch_bounds__(512, 2) void jacobi_kernel(float* __restrict__ G) {
    int b = blockIdx.x;
    float* Gb = G + (size_t)b * NH * CSTRIDE;
    __shared__ float lam[NH];
    int tid = threadIdx.x, lane = tid & 63, wid = tid >> 6;  // 8 waves
    for (int k = 0; k < 28; ++k) {
        int j = wid * 28 + k;
        float4 v = ((const float4*)(Gb + j * CSTRIDE))[lane];
        float d = dot4(v, v);
        d += __shfl_xor(d, 32); d += __shfl_xor(d, 16); d += __shfl_xor(d, 8);
        d += __shfl_xor(d, 4);  d += __shfl_xor(d, 2);  d += __shfl_xor(d, 1);
        if (lane == 0) lam[j] = d;
    }
    __syncthreads();
    for (int sweep = 0; sweep < NSWEEPS; ++sweep) {
        for (int r = 0; r < 15; ++r) {
            int bp, bq;
            if (wid == 0) {
                bp = 15; bq = r;
            } else {
                bp = r + wid; if (bp >= 15) bp -= 15;
                bq = r - wid; if (bq < 0) bq += 15;
            }
            int cp0 = bp * 14, cq0 = bq * 14;
            float4 c[28];
            float l[28];
#pragma unroll
            for (int k = 0; k < 14; ++k) {
                c[k]      = ((const float4*)(Gb + (cp0 + k) * CSTRIDE))[lane];
                c[14 + k] = ((const float4*)(Gb + (cq0 + k) * CSTRIDE))[lane];
                l[k]      = lam[cp0 + k];
                l[14 + k] = lam[cq0 + k];
            }
            if (r == 0) {
                // intra-block: circle schedule, 13 mini-rounds x 7 pairs
                // per half -> 14 interleaved reductions per tree.
#pragma unroll
                for (int t = 0; t < 13; ++t) {
                    float apq[14];
#pragma unroll
                    for (int u = 0; u < 14; ++u) {
                        int h = (u < 7) ? 0 : 14;
                        int i = u % 7;
                        int p = h + ((i == 0) ? 13 : (t + i) % 13);
                        int q = h + ((i == 0) ? t : (t + 13 - i) % 13);
                        apq[u] = dot4(c[p], c[q]);
                    }
#pragma unroll
                    for (int o = 32; o; o >>= 1)
#pragma unroll
                        for (int u = 0; u < 14; ++u)
                            apq[u] += __shfl_xor(apq[u], o);
#pragma unroll
                    for (int u = 0; u < 14; ++u) {
                        int h = (u < 7) ? 0 : 14;
                        int i = u % 7;
                        int p = h + ((i == 0) ? 13 : (t + i) % 13);
                        int q = h + ((i == 0) ? t : (t + 13 - i) % 13);
                        apply_rot(c[p], c[q], l[p], l[q], apq[u]);
                    }
                }
            }
            // cross-block: 14 mini-rounds x 14 disjoint pairs
#pragma unroll
            for (int s = 0; s < 14; ++s) {
                float apq[14];
#pragma unroll
                for (int k = 0; k < 14; ++k) {
                    int q = 14 + ((k + s) % 14);
                    apq[k] = dot4(c[k], c[q]);
                }
#pragma unroll
                for (int o = 32; o; o >>= 1)
#pragma unroll
                    for (int k = 0; k < 14; ++k)
                        apq[k] += __shfl_xor(apq[k], o);
#pragma unroll
                for (int k = 0; k < 14; ++k) {
                    int q = 14 + ((k + s) % 14);
                    apply_rot(c[k], c[q], l[k], l[q], apq[k]);
                }
            }
#pragma unroll
            for (int k = 0; k < 14; ++k) {
                ((float4*)(Gb + (cp0 + k) * CSTRIDE))[lane] = c[k];
                ((float4*)(Gb + (cq0 + k) * CSTRIDE))[lane] = c[14 + k];
                if (lane == 0) {
                    lam[cp0 + k] = l[k];
                    lam[cq0 + k] = l[14 + k];
                }
            }
            __syncthreads();
        }
    }
}

// --------------------------------- exact norms + select 45 smallest
__global__ __launch_bounds__(256) void select_kernel(const float* __restrict__ G,
                                                     int* __restrict__ tail_idx,
                                                     float* __restrict__ invl2) {
    int b = blockIdx.x;
    const float* Gb = G + (size_t)b * NH * CSTRIDE;
    __shared__ float lam[NH];
    __shared__ int cnt;
    int tid = threadIdx.x, lane = tid & 63, wid = tid >> 6;  // 4 waves
    if (tid == 0) cnt = 0;
    for (int j = wid * 56; j < wid * 56 + 56; ++j) {
        float4 v = ((const float4*)(Gb + j * CSTRIDE))[lane];
        float d = dot4(v, v);
        d += __shfl_xor(d, 32); d += __shfl_xor(d, 16); d += __shfl_xor(d, 8);
        d += __shfl_xor(d, 4);  d += __shfl_xor(d, 2);  d += __shfl_xor(d, 1);
        if (lane == 0) lam[j] = d;
    }
    __syncthreads();
    if (tid < NH) {
        float my = lam[tid];
        int rank = 0;
        for (int i = 0; i < NH; ++i) {
            float o = lam[i];
            rank += (o > my) ? 1 : ((o == my && i < tid) ? 1 : 0);
        }
        if (rank >= KKEEP) {
            int pos = atomicAdd(&cnt, 1);
            tail_idx[b * NTAIL + pos] = tid;
            invl2[b * NTAIL + pos] = 1.f / my;  // ||col||^2 = lambda^2
        }
    }
}

// ------------------------------- C[b][t][w'] = (col_t^T A)[w'] / lambda^2
__global__ __launch_bounds__(128) void ctail_kernel(const float* __restrict__ G,
                                                    const float* __restrict__ x,
                                                    const int* __restrict__ mask,
                                                    const int* __restrict__ tail_idx,
                                                    const float* __restrict__ invl2,
                                                    float* __restrict__ C) {
    int b = blockIdx.y;
    int wchunk = blockIdx.x;  // 6 chunks of 112
    __shared__ float sT[NTAIL * NH];
    __shared__ float sInv[NTAIL];
    __shared__ int sIdx[NTAIL];
    int tid = threadIdx.x;
    if (tid < NTAIL) {
        sIdx[tid] = tail_idx[b * NTAIL + tid];
        sInv[tid] = invl2[b * NTAIL + tid];
    }
    __syncthreads();
    for (int idx = tid; idx < NTAIL * NH; idx += 128) {
        int t = idx / NH, h = idx - t * NH;
        sT[idx] = G[((size_t)b * NH + sIdx[t]) * CSTRIDE + h];
    }
    __syncthreads();
    if (tid < 112) {
        int wp = wchunk * 112 + tid;
        int c = wp / NH;
        int w = wp - c * NH;
        const float* xb = x + ((size_t)(b * 3 + c) * NH) * NH + w;
        const int* mb = mask + (size_t)b * NH * NCW + wp;
        float acc[NTAIL];
#pragma unroll
        for (int t = 0; t < NTAIL; ++t) acc[t] = 0.f;
        for (int h = 0; h < NH; ++h) {
            float a = mb[h * NCW] ? 2.f * xb[h * NH] - 1.f : 0.f;
#pragma unroll
            for (int t = 0; t < NTAIL; ++t) acc[t] += sT[t * NH + h] * a;
        }
        float* Cb = C + ((size_t)b * NTAIL) * NCW + wp;
#pragma unroll
        for (int t = 0; t < NTAIL; ++t) Cb[t * NCW] = acc[t] * sInv[t];
    }
}

// ----------------------------------------------------------- final output
__global__ __launch_bounds__(256) void out_kernel(const float* __restrict__ G,
                                                  const float* __restrict__ x,
                                                  const int* __restrict__ mask,
                                                  const int* __restrict__ tail_idx,
                                                  const float* __restrict__ C,
                                                  const float* __restrict__ invp,
                                                  float* __restrict__ out) {
    int b = blockIdx.z, hc = blockIdx.y, wc = blockIdx.x;
    int h0 = hc * 32, w0 = wc * 96;
    __shared__ float sCol[NTAIL * 32];
    __shared__ float sC[NTAIL * 96];
    __shared__ int sIdx[NTAIL];
    int tid = threadIdx.x;
    if (tid < NTAIL) sIdx[tid] = tail_idx[b * NTAIL + tid];
    __syncthreads();
    for (int i = tid; i < NTAIL * 32; i += 256) {
        int t = i >> 5, hl = i & 31;
        sCol[i] = G[((size_t)b * NH + sIdx[t]) * CSTRIDE + h0 + hl];
    }
    for (int i = tid; i < NTAIL * 96; i += 256) {
        int t = i / 96, wl = i - t * 96;
        sC[i] = C[((size_t)b * NTAIL + t) * NCW + w0 + wl];
    }
    __syncthreads();
    float ip = invp[b];
    for (int i = tid; i < 32 * 96; i += 256) {
        int hl = i / 96, wl = i - hl * 96;
        int h = h0 + hl, wp = w0 + wl;
        int c = wp / NH, w = wp - c * NH;
        float a = mask[(size_t)b * NH * NCW + h * NCW + wp]
                      ? 2.f * x[((size_t)(b * 3 + c) * NH + h) * NH + w] - 1.f
                      : 0.f;
        float corr = 0.f;
#pragma unroll
        for (int t = 0; t < NTAIL; ++t) corr += sCol[t * 32 + hl] * sC[t * 96 + wl];
        float val = (a - corr) * ip;
        val = fminf(1.f, fmaxf(-1.f, val));
        out[((size_t)(b * 3 + c) * NH + h) * NH + w] = (val + 1.f) * 0.5f;
    }
}

extern "C" void kernel_launch(void* const* d_in, const int* in_sizes, int n_in,
                              void* d_out, int out_size, void* d_ws, size_t ws_size,
                              hipStream_t stream) {
    const float* x = (const float*)d_in[0];
    const int* mask = (const int*)d_in[1];
    float* out = (float*)d_out;
    char* ws = (char*)d_ws;

    const size_t off_G = 0;
    const size_t sz_G = (size_t)BATCH * NH * CSTRIDE * 4;
    const size_t off_invp = off_G + sz_G;
    const size_t off_tail = off_invp + 256;
    const size_t off_invl2 = off_tail + (size_t)BATCH * NTAIL * 4;
    const size_t off_C = off_invl2 + (size_t)BATCH * NTAIL * 4;

    float* G = (float*)(ws + off_G);
    float* invp = (float*)(ws + off_invp);
    int* tail = (int*)(ws + off_tail);
    float* invl2 = (float*)(ws + off_invl2);
    float* C = (float*)(ws + off_C);

    pobs_kernel<<<BATCH, 256, 0, stream>>>(mask, invp);
    pad_kernel<<<(BATCH * NH * 32) / 256, 256, 0, stream>>>(G);
    gram_kernel<<<dim3(49, BATCH), 256, 0, stream>>>(x, mask, G);
    jacobi_kernel<<<BATCH, 512, 0, stream>>>(G);
    select_kernel<<<BATCH, 256, 0, stream>>>(G, tail, invl2);
    ctail_kernel<<<dim3(6, BATCH), 128, 0, stream>>>(G, x, mask, tail, invl2, C);
    out_kernel<<<dim3(7, 7, BATCH), 256, 0, stream>>>(G, x, mask, tail, C, invp, out);
}

// Round 7
// 36573.224 us; speedup vs baseline: 1.6470x; 1.0830x over previous
//
#include <hip/hip_runtime.h>

#define BATCH 64
#define NH 224          // rows of img2d (and eigen dimension)
#define NCW 672         // cols of img2d
#define CSTRIDE 256     // padded column stride for G (224 data + 32 zero pad)
#define KKEEP 179       // int(0.8*224)
#define NTAIL 45        // 224 - 179
#define NSWEEPS 10
#define EPS2 1e-18f

__device__ __forceinline__ float fast_rcp(float x) { return __builtin_amdgcn_rcpf(x); }
__device__ __forceinline__ float fast_rsq(float x) { return __builtin_amdgcn_rsqf(x); }
__device__ __forceinline__ float fast_sqrt(float x) { return __builtin_amdgcn_sqrtf(x); }

__device__ __forceinline__ float dot4(const float4& a, const float4& b) {
    return a.x * b.x + a.y * b.y + a.z * b.z + a.w * b.w;
}

// Intra-block disjoint pair schedule: 7 mini-rounds x 3 pairs, i+j == t (mod 7)
constexpr int IP[7][3][2] = {
    {{1, 6}, {2, 5}, {3, 4}},
    {{0, 1}, {2, 6}, {3, 5}},
    {{0, 2}, {3, 6}, {4, 5}},
    {{0, 3}, {1, 2}, {4, 6}},
    {{0, 4}, {1, 3}, {5, 6}},
    {{0, 5}, {1, 4}, {2, 3}},
    {{0, 6}, {1, 5}, {2, 4}}};

// Unconditional (select-guarded) Jacobi rotation given the reduced dot apq.
__device__ __forceinline__ void apply_rot(float4& A, float4& B, float& LA,
                                          float& LB, float apq) {
    float tau = (LB - LA) * 0.5f * fast_rcp(apq);
    float tt = copysignf(fast_rcp(fabsf(tau) + fast_sqrt(1.f + tau * tau)), tau);
    tt = (apq * apq > EPS2 * LA * LB) ? tt : 0.f;
    float cc = fast_rsq(1.f + tt * tt);
    float ss = tt * cc;
    float ax = A.x, ay = A.y, az = A.z, aw = A.w;
    A.x = cc * ax - ss * B.x; B.x = ss * ax + cc * B.x;
    A.y = cc * ay - ss * B.y; B.y = ss * ay + cc * B.y;
    A.z = cc * az - ss * B.z; B.z = ss * az + cc * B.z;
    A.w = cc * aw - ss * B.w; B.w = ss * aw + cc * B.w;
    LA -= tt * apq; LB += tt * apq;
}

// ---------------------------------------------------------------- p_obs
__global__ __launch_bounds__(256) void pobs_kernel(const int* __restrict__ mask,
                                                   float* __restrict__ invp) {
    int b = blockIdx.x, tid = threadIdx.x;
    const int* mb = mask + (size_t)b * NH * NCW;
    int s = 0;
    for (int i = tid; i < NH * NCW; i += 256) s += mb[i];
    __shared__ int red[256];
    red[tid] = s;
    __syncthreads();
    for (int o = 128; o; o >>= 1) {
        if (tid < o) red[tid] += red[tid + o];
        __syncthreads();
    }
    if (tid == 0) invp[b] = (float)(NH * NCW) / (float)red[0];
}

// ------------------------------------------------- zero the pad rows of G
__global__ void pad_kernel(float* __restrict__ G) {
    int idx = blockIdx.x * 256 + threadIdx.x;  // BATCH*224*32 total
    int b = idx / (NH * 32);
    int rem = idx - b * (NH * 32);
    int j = rem >> 5;
    int i = NH + (rem & 31);
    G[((size_t)b * NH + j) * CSTRIDE + i] = 0.f;
}

// ------------------------------------------------------- G = A * A^T
__global__ __launch_bounds__(256) void gram_kernel(const float* __restrict__ x,
                                                   const int* __restrict__ mask,
                                                   float* __restrict__ G) {
    int b = blockIdx.y;
    int tile = blockIdx.x;       // 0..48
    int ti = tile / 7, tj = tile - ti * 7;
    int i0 = ti * 32, j0 = tj * 32;
    __shared__ float As[32][33];
    __shared__ float Bs[32][33];
    int tid = threadIdx.x;
    int tx = tid & 31;
    int ty = tid >> 5;
    float acc0 = 0, acc1 = 0, acc2 = 0, acc3 = 0;
    const float* xb = x + (size_t)b * 3 * NH * NH;
    const int* mb = mask + (size_t)b * NH * NCW;
    for (int ks = 0; ks < 21; ++ks) {
        int k0 = ks * 32;
        int c = k0 / NH;
        int w0 = k0 - c * NH;
        __syncthreads();
        for (int l = tid; l < 1024; l += 256) {
            int dk = l & 31, di = l >> 5;
            int hA = i0 + di, hB = j0 + di;
            float xa = xb[(c * NH + hA) * NH + w0 + dk];
            float xc = xb[(c * NH + hB) * NH + w0 + dk];
            As[di][dk] = mb[hA * NCW + k0 + dk] ? 2.f * xa - 1.f : 0.f;
            Bs[di][dk] = mb[hB * NCW + k0 + dk] ? 2.f * xc - 1.f : 0.f;
        }
        __syncthreads();
#pragma unroll
        for (int kk = 0; kk < 32; ++kk) {
            float bv = Bs[tx][kk];
            acc0 += As[ty][kk] * bv;
            acc1 += As[ty + 8][kk] * bv;
            acc2 += As[ty + 16][kk] * bv;
            acc3 += As[ty + 24][kk] * bv;
        }
    }
    float* Gb = G + (size_t)b * NH * CSTRIDE;
    int j = j0 + tx;
    Gb[j * CSTRIDE + i0 + ty] = acc0;
    Gb[j * CSTRIDE + i0 + ty + 8] = acc1;
    Gb[j * CSTRIDE + i0 + ty + 16] = acc2;
    Gb[j * CSTRIDE + i0 + ty + 24] = acc3;
}

// ---------------------------------------------- blocked one-sided Jacobi
// 32 blocks x 7 columns; tournament: 31 rounds x 16 block-pairs.
// 512-thread WG (8 waves), each wave serves 2 pairs per round via a
// NON-unrolled rep loop: body appears once (R3-size, promotable), c[14]
// (56 VGPRs) is SROA'd per iteration. launch_bounds(512,1) -> VGPR cap 512
// so the allocator has headroom (1024-thread WGs pinned 64-128 and spilled).
__global__ __launch_bounds__(512, 1) void jacobi_kernel(float* __restrict__ G) {
    int b = blockIdx.x;
    float* Gb = G + (size_t)b * NH * CSTRIDE;
    __shared__ float lam[NH];
    int tid = threadIdx.x, lane = tid & 63, wid = tid >> 6;  // 8 waves
    for (int k = 0; k < 28; ++k) {
        int j = wid * 28 + k;
        float4 v = ((const float4*)(Gb + j * CSTRIDE))[lane];
        float d = dot4(v, v);
        d += __shfl_xor(d, 32); d += __shfl_xor(d, 16); d += __shfl_xor(d, 8);
        d += __shfl_xor(d, 4);  d += __shfl_xor(d, 2);  d += __shfl_xor(d, 1);
        if (lane == 0) lam[j] = d;
    }
    __syncthreads();
    for (int sweep = 0; sweep < NSWEEPS; ++sweep) {
        for (int r = 0; r < 31; ++r) {
#pragma unroll 1
            for (int rep = 0; rep < 2; ++rep) {
                int pid = rep * 8 + wid;  // 0..15
                int bp, bq;
                if (pid == 0) {
                    bp = 31; bq = r;
                } else {
                    bp = r + pid; if (bp >= 31) bp -= 31;
                    bq = r - pid; if (bq < 0) bq += 31;
                }
                int cp0 = bp * 7, cq0 = bq * 7;
                float4 c[14];
                float l[14];
#pragma unroll
                for (int k = 0; k < 7; ++k) {
                    c[k]     = ((const float4*)(Gb + (cp0 + k) * CSTRIDE))[lane];
                    c[7 + k] = ((const float4*)(Gb + (cq0 + k) * CSTRIDE))[lane];
                    l[k]     = lam[cp0 + k];
                    l[7 + k] = lam[cq0 + k];
                }
                if (r == 0) {
                    // intra-block: 7 mini-rounds x 6 disjoint pairs
#pragma unroll
                    for (int t = 0; t < 7; ++t) {
                        float apq[6];
#pragma unroll
                        for (int k = 0; k < 6; ++k) {
                            int p = IP[t][k % 3][0] + (k < 3 ? 0 : 7);
                            int q = IP[t][k % 3][1] + (k < 3 ? 0 : 7);
                            apq[k] = dot4(c[p], c[q]);
                        }
#pragma unroll
                        for (int o = 32; o; o >>= 1)
#pragma unroll
                            for (int k = 0; k < 6; ++k)
                                apq[k] += __shfl_xor(apq[k], o);
#pragma unroll
                        for (int k = 0; k < 6; ++k) {
                            int p = IP[t][k % 3][0] + (k < 3 ? 0 : 7);
                            int q = IP[t][k % 3][1] + (k < 3 ? 0 : 7);
                            apply_rot(c[p], c[q], l[p], l[q], apq[k]);
                        }
                    }
                }
                // cross-block: 7 mini-rounds x 7 disjoint pairs
#pragma unroll
                for (int s = 0; s < 7; ++s) {
                    float apq[7];
#pragma unroll
                    for (int k = 0; k < 7; ++k) {
                        int q = 7 + ((k + s) % 7);
                        apq[k] = dot4(c[k], c[q]);
                    }
#pragma unroll
                    for (int o = 32; o; o >>= 1)
#pragma unroll
                        for (int k = 0; k < 7; ++k)
                            apq[k] += __shfl_xor(apq[k], o);
#pragma unroll
                    for (int k = 0; k < 7; ++k) {
                        int q = 7 + ((k + s) % 7);
                        apply_rot(c[k], c[q], l[k], l[q], apq[k]);
                    }
                }
#pragma unroll
                for (int k = 0; k < 7; ++k) {
                    ((float4*)(Gb + (cp0 + k) * CSTRIDE))[lane] = c[k];
                    ((float4*)(Gb + (cq0 + k) * CSTRIDE))[lane] = c[7 + k];
                    if (lane == 0) {
                        lam[cp0 + k] = l[k];
                        lam[cq0 + k] = l[7 + k];
                    }
                }
            }
            __syncthreads();
        }
    }
}

// --------------------------------- exact norms + select 45 smallest
__global__ __launch_bounds__(256) void select_kernel(const float* __restrict__ G,
                                                     int* __restrict__ tail_idx,
                                                     float* __restrict__ invl2) {
    int b = blockIdx.x;
    const float* Gb = G + (size_t)b * NH * CSTRIDE;
    __shared__ float lam[NH];
    __shared__ int cnt;
    int tid = threadIdx.x, lane = tid & 63, wid = tid >> 6;  // 4 waves
    if (tid == 0) cnt = 0;
    for (int j = wid * 56; j < wid * 56 + 56; ++j) {
        float4 v = ((const float4*)(Gb + j * CSTRIDE))[lane];
        float d = dot4(v, v);
        d += __shfl_xor(d, 32); d += __shfl_xor(d, 16); d += __shfl_xor(d, 8);
        d += __shfl_xor(d, 4);  d += __shfl_xor(d, 2);  d += __shfl_xor(d, 1);
        if (lane == 0) lam[j] = d;
    }
    __syncthreads();
    if (tid < NH) {
        float my = lam[tid];
        int rank = 0;
        for (int i = 0; i < NH; ++i) {
            float o = lam[i];
            rank += (o > my) ? 1 : ((o == my && i < tid) ? 1 : 0);
        }
        if (rank >= KKEEP) {
            int pos = atomicAdd(&cnt, 1);
            tail_idx[b * NTAIL + pos] = tid;
            invl2[b * NTAIL + pos] = 1.f / my;  // ||col||^2 = lambda^2
        }
    }
}

// ------------------------------- C[b][t][w'] = (col_t^T A)[w'] / lambda^2
__global__ __launch_bounds__(128) void ctail_kernel(const float* __restrict__ G,
                                                    const float* __restrict__ x,
                                                    const int* __restrict__ mask,
                                                    const int* __restrict__ tail_idx,
                                                    const float* __restrict__ invl2,
                                                    float* __restrict__ C) {
    int b = blockIdx.y;
    int wchunk = blockIdx.x;  // 6 chunks of 112
    __shared__ float sT[NTAIL * NH];
    __shared__ float sInv[NTAIL];
    __shared__ int sIdx[NTAIL];
    int tid = threadIdx.x;
    if (tid < NTAIL) {
        sIdx[tid] = tail_idx[b * NTAIL + tid];
        sInv[tid] = invl2[b * NTAIL + tid];
    }
    __syncthreads();
    for (int idx = tid; idx < NTAIL * NH; idx += 128) {
        int t = idx / NH, h = idx - t * NH;
        sT[idx] = G[((size_t)b * NH + sIdx[t]) * CSTRIDE + h];
    }
    __syncthreads();
    if (tid < 112) {
        int wp = wchunk * 112 + tid;
        int c = wp / NH;
        int w = wp - c * NH;
        const float* xb = x + ((size_t)(b * 3 + c) * NH) * NH + w;
        const int* mb = mask + (size_t)b * NH * NCW + wp;
        float acc[NTAIL];
#pragma unroll
        for (int t = 0; t < NTAIL; ++t) acc[t] = 0.f;
        for (int h = 0; h < NH; ++h) {
            float a = mb[h * NCW] ? 2.f * xb[h * NH] - 1.f : 0.f;
#pragma unroll
            for (int t = 0; t < NTAIL; ++t) acc[t] += sT[t * NH + h] * a;
        }
        float* Cb = C + ((size_t)b * NTAIL) * NCW + wp;
#pragma unroll
        for (int t = 0; t < NTAIL; ++t) Cb[t * NCW] = acc[t] * sInv[t];
    }
}

// ----------------------------------------------------------- final output
__global__ __launch_bounds__(256) void out_kernel(const float* __restrict__ G,
                                                  const float* __restrict__ x,
                                                  const int* __restrict__ mask,
                                                  const int* __restrict__ tail_idx,
                                                  const float* __restrict__ C,
                                                  const float* __restrict__ invp,
                                                  float* __restrict__ out) {
    int b = blockIdx.z, hc = blockIdx.y, wc = blockIdx.x;
    int h0 = hc * 32, w0 = wc * 96;
    __shared__ float sCol[NTAIL * 32];
    __shared__ float sC[NTAIL * 96];
    __shared__ int sIdx[NTAIL];
    int tid = threadIdx.x;
    if (tid < NTAIL) sIdx[tid] = tail_idx[b * NTAIL + tid];
    __syncthreads();
    for (int i = tid; i < NTAIL * 32; i += 256) {
        int t = i >> 5, hl = i & 31;
        sCol[i] = G[((size_t)b * NH + sIdx[t]) * CSTRIDE + h0 + hl];
    }
    for (int i = tid; i < NTAIL * 96; i += 256) {
        int t = i / 96, wl = i - t * 96;
        sC[i] = C[((size_t)b * NTAIL + t) * NCW + w0 + wl];
    }
    __syncthreads();
    float ip = invp[b];
    for (int i = tid; i < 32 * 96; i += 256) {
        int hl = i / 96, wl = i - hl * 96;
        int h = h0 + hl, wp = w0 + wl;
        int c = wp / NH, w = wp - c * NH;
        float a = mask[(size_t)b * NH * NCW + h * NCW + wp]
                      ? 2.f * x[((size_t)(b * 3 + c) * NH + h) * NH + w] - 1.f
                      : 0.f;
        float corr = 0.f;
#pragma unroll
        for (int t = 0; t < NTAIL; ++t) corr += sCol[t * 32 + hl] * sC[t * 96 + wl];
        float val = (a - corr) * ip;
        val = fminf(1.f, fmaxf(-1.f, val));
        out[((size_t)(b * 3 + c) * NH + h) * NH + w] = (val + 1.f) * 0.5f;
    }
}

extern "C" void kernel_launch(void* const* d_in, const int* in_sizes, int n_in,
                              void* d_out, int out_size, void* d_ws, size_t ws_size,
                              hipStream_t stream) {
    const float* x = (const float*)d_in[0];
    const int* mask = (const int*)d_in[1];
    float* out = (float*)d_out;
    char* ws = (char*)d_ws;

    const size_t off_G = 0;
    const size_t sz_G = (size_t)BATCH * NH * CSTRIDE * 4;
    const size_t off_invp = off_G + sz_G;
    const size_t off_tail = off_invp + 256;
    const size_t off_invl2 = off_tail + (size_t)BATCH * NTAIL * 4;
    const size_t off_C = off_invl2 + (size_t)BATCH * NTAIL * 4;

    float* G = (float*)(ws + off_G);
    float* invp = (float*)(ws + off_invp);
    int* tail = (int*)(ws + off_tail);
    float* invl2 = (float*)(ws + off_invl2);
    float* C = (float*)(ws + off_C);

    pobs_kernel<<<BATCH, 256, 0, stream>>>(mask, invp);
    pad_kernel<<<(BATCH * NH * 32) / 256, 256, 0, stream>>>(G);
    gram_kernel<<<dim3(49, BATCH), 256, 0, stream>>>(x, mask, G);
    jacobi_kernel<<<BATCH, 512, 0, stream>>>(G);
    select_kernel<<<BATCH, 256, 0, stream>>>(G, tail, invl2);
    ctail_kernel<<<dim3(6, BATCH), 128, 0, stream>>>(G, x, mask, tail, invl2, C);
    out_kernel<<<dim3(7, 7, BATCH), 256, 0, stream>>>(G, x, mask, tail, C, invp, out);
}

// Round 8
// 7822.289 us; speedup vs baseline: 7.7007x; 4.6755x over previous
//
#include <hip/hip_runtime.h>

#define BATCH 64
#define NH 224          // rows of img2d (and eigen dimension)
#define NCW 672         // cols of img2d
#define CSTRIDE 256     // padded column stride for G (224 data + 32 zero pad)
#define KKEEP 179       // int(0.8*224)
#define NTAIL 45        // 224 - 179
#define NSWEEPS 10
#define EPS2 1e-18f

__device__ __forceinline__ float fast_rcp(float x) { return __builtin_amdgcn_rcpf(x); }
__device__ __forceinline__ float fast_rsq(float x) { return __builtin_amdgcn_rsqf(x); }
__device__ __forceinline__ float fast_sqrt(float x) { return __builtin_amdgcn_sqrtf(x); }

__device__ __forceinline__ float dot4(const float4& a, const float4& b) {
    return a.x * b.x + a.y * b.y + a.z * b.z + a.w * b.w;
}

// Unconditional (select-guarded) Jacobi rotation given the reduced dot apq.
__device__ __forceinline__ void apply_rot(float4& A, float4& B, float& LA,
                                          float& LB, float apq) {
    float tau = (LB - LA) * 0.5f * fast_rcp(apq);
    float tt = copysignf(fast_rcp(fabsf(tau) + fast_sqrt(1.f + tau * tau)), tau);
    tt = (apq * apq > EPS2 * LA * LB) ? tt : 0.f;
    float cc = fast_rsq(1.f + tt * tt);
    float ss = tt * cc;
    float ax = A.x, ay = A.y, az = A.z, aw = A.w;
    A.x = cc * ax - ss * B.x; B.x = ss * ax + cc * B.x;
    A.y = cc * ay - ss * B.y; B.y = ss * ay + cc * B.y;
    A.z = cc * az - ss * B.z; B.z = ss * az + cc * B.z;
    A.w = cc * aw - ss * B.w; B.w = ss * aw + cc * B.w;
    LA -= tt * apq; LB += tt * apq;
}

// --- macro-expanded schedule on NAMED scalars (no alloca -> no SROA failure;
// --- R3-R7 kept float4 c[14] arrays: variable-indexed at SROA time (SROA
// --- runs pre-unroll) -> scratch-allocated -> 4+ GB spill traffic).
#define REDL7(o) a0 += __shfl_xor(a0, o); a1 += __shfl_xor(a1, o); \
    a2 += __shfl_xor(a2, o); a3 += __shfl_xor(a3, o); a4 += __shfl_xor(a4, o); \
    a5 += __shfl_xor(a5, o); a6 += __shfl_xor(a6, o);
#define REDL6(o) a0 += __shfl_xor(a0, o); a1 += __shfl_xor(a1, o); \
    a2 += __shfl_xor(a2, o); a3 += __shfl_xor(a3, o); a4 += __shfl_xor(a4, o); \
    a5 += __shfl_xor(a5, o);

#define CROSS_MR(j0, j1, j2, j3, j4, j5, j6) do {                         \
    float a0 = dot4(c0, c##j0), a1 = dot4(c1, c##j1);                     \
    float a2 = dot4(c2, c##j2), a3 = dot4(c3, c##j3);                     \
    float a4 = dot4(c4, c##j4), a5 = dot4(c5, c##j5);                     \
    float a6 = dot4(c6, c##j6);                                           \
    REDL7(32) REDL7(16) REDL7(8) REDL7(4) REDL7(2) REDL7(1)               \
    apply_rot(c0, c##j0, l0, l##j0, a0);                                  \
    apply_rot(c1, c##j1, l1, l##j1, a1);                                  \
    apply_rot(c2, c##j2, l2, l##j2, a2);                                  \
    apply_rot(c3, c##j3, l3, l##j3, a3);                                  \
    apply_rot(c4, c##j4, l4, l##j4, a4);                                  \
    apply_rot(c5, c##j5, l5, l##j5, a5);                                  \
    apply_rot(c6, c##j6, l6, l##j6, a6);                                  \
} while (0)

#define INTRA_MR(p0, q0, p1, q1, p2, q2, p3, q3, p4, q4, p5, q5) do {     \
    float a0 = dot4(c##p0, c##q0), a1 = dot4(c##p1, c##q1);               \
    float a2 = dot4(c##p2, c##q2), a3 = dot4(c##p3, c##q3);               \
    float a4 = dot4(c##p4, c##q4), a5 = dot4(c##p5, c##q5);               \
    REDL6(32) REDL6(16) REDL6(8) REDL6(4) REDL6(2) REDL6(1)               \
    apply_rot(c##p0, c##q0, l##p0, l##q0, a0);                            \
    apply_rot(c##p1, c##q1, l##p1, l##q1, a1);                            \
    apply_rot(c##p2, c##q2, l##p2, l##q2, a2);                            \
    apply_rot(c##p3, c##q3, l##p3, l##q3, a3);                            \
    apply_rot(c##p4, c##q4, l##p4, l##q4, a4);                            \
    apply_rot(c##p5, c##q5, l##p5, l##q5, a5);                            \
} while (0)

// ---------------------------------------------------------------- p_obs
__global__ __launch_bounds__(256) void pobs_kernel(const int* __restrict__ mask,
                                                   float* __restrict__ invp) {
    int b = blockIdx.x, tid = threadIdx.x;
    const int* mb = mask + (size_t)b * NH * NCW;
    int s = 0;
    for (int i = tid; i < NH * NCW; i += 256) s += mb[i];
    __shared__ int red[256];
    red[tid] = s;
    __syncthreads();
    for (int o = 128; o; o >>= 1) {
        if (tid < o) red[tid] += red[tid + o];
        __syncthreads();
    }
    if (tid == 0) invp[b] = (float)(NH * NCW) / (float)red[0];
}

// ------------------------------------------------- zero the pad rows of G
__global__ void pad_kernel(float* __restrict__ G) {
    int idx = blockIdx.x * 256 + threadIdx.x;  // BATCH*224*32 total
    int b = idx / (NH * 32);
    int rem = idx - b * (NH * 32);
    int j = rem >> 5;
    int i = NH + (rem & 31);
    G[((size_t)b * NH + j) * CSTRIDE + i] = 0.f;
}

// ------------------------------------------------------- G = A * A^T
__global__ __launch_bounds__(256) void gram_kernel(const float* __restrict__ x,
                                                   const int* __restrict__ mask,
                                                   float* __restrict__ G) {
    int b = blockIdx.y;
    int tile = blockIdx.x;       // 0..48
    int ti = tile / 7, tj = tile - ti * 7;
    int i0 = ti * 32, j0 = tj * 32;
    __shared__ float As[32][33];
    __shared__ float Bs[32][33];
    int tid = threadIdx.x;
    int tx = tid & 31;
    int ty = tid >> 5;
    float acc0 = 0, acc1 = 0, acc2 = 0, acc3 = 0;
    const float* xb = x + (size_t)b * 3 * NH * NH;
    const int* mb = mask + (size_t)b * NH * NCW;
    for (int ks = 0; ks < 21; ++ks) {
        int k0 = ks * 32;
        int c = k0 / NH;
        int w0 = k0 - c * NH;
        __syncthreads();
        for (int l = tid; l < 1024; l += 256) {
            int dk = l & 31, di = l >> 5;
            int hA = i0 + di, hB = j0 + di;
            float xa = xb[(c * NH + hA) * NH + w0 + dk];
            float xc = xb[(c * NH + hB) * NH + w0 + dk];
            As[di][dk] = mb[hA * NCW + k0 + dk] ? 2.f * xa - 1.f : 0.f;
            Bs[di][dk] = mb[hB * NCW + k0 + dk] ? 2.f * xc - 1.f : 0.f;
        }
        __syncthreads();
#pragma unroll
        for (int kk = 0; kk < 32; ++kk) {
            float bv = Bs[tx][kk];
            acc0 += As[ty][kk] * bv;
            acc1 += As[ty + 8][kk] * bv;
            acc2 += As[ty + 16][kk] * bv;
            acc3 += As[ty + 24][kk] * bv;
        }
    }
    float* Gb = G + (size_t)b * NH * CSTRIDE;
    int j = j0 + tx;
    Gb[j * CSTRIDE + i0 + ty] = acc0;
    Gb[j * CSTRIDE + i0 + ty + 8] = acc1;
    Gb[j * CSTRIDE + i0 + ty + 16] = acc2;
    Gb[j * CSTRIDE + i0 + ty + 24] = acc3;
}

// ---------------------------------------------- blocked one-sided Jacobi
// 32 blocks x 7 columns; tournament: 31 rounds x 16 block-pairs; 8 waves,
// each serving 2 pairs per round. Columns are 14 NAMED float4 scalars.
__global__ __launch_bounds__(512, 1) void jacobi_kernel(float* __restrict__ G) {
    int b = blockIdx.x;
    float* Gb = G + (size_t)b * NH * CSTRIDE;
    __shared__ float lam[NH];
    int tid = threadIdx.x, lane = tid & 63, wid = tid >> 6;  // 8 waves
    for (int k = 0; k < 28; ++k) {
        int j = wid * 28 + k;
        float4 v = ((const float4*)(Gb + j * CSTRIDE))[lane];
        float d = dot4(v, v);
        d += __shfl_xor(d, 32); d += __shfl_xor(d, 16); d += __shfl_xor(d, 8);
        d += __shfl_xor(d, 4);  d += __shfl_xor(d, 2);  d += __shfl_xor(d, 1);
        if (lane == 0) lam[j] = d;
    }
    __syncthreads();
    for (int sweep = 0; sweep < NSWEEPS; ++sweep) {
        for (int r = 0; r < 31; ++r) {
#pragma unroll 1
            for (int rep = 0; rep < 2; ++rep) {
                int pid = rep * 8 + wid;  // 0..15
                int bp, bq;
                if (pid == 0) {
                    bp = 31; bq = r;
                } else {
                    bp = r + pid; if (bp >= 31) bp -= 31;
                    bq = r - pid; if (bq < 0) bq += 31;
                }
                int cp0 = bp * 7, cq0 = bq * 7;
                float4* colp = (float4*)(Gb + cp0 * CSTRIDE) + lane;
                float4* colq = (float4*)(Gb + cq0 * CSTRIDE) + lane;
                float4 c0 = colp[0 * 64], c1 = colp[1 * 64], c2 = colp[2 * 64];
                float4 c3 = colp[3 * 64], c4 = colp[4 * 64], c5 = colp[5 * 64];
                float4 c6 = colp[6 * 64];
                float4 c7 = colq[0 * 64], c8 = colq[1 * 64], c9 = colq[2 * 64];
                float4 c10 = colq[3 * 64], c11 = colq[4 * 64], c12 = colq[5 * 64];
                float4 c13 = colq[6 * 64];
                float l0 = lam[cp0 + 0], l1 = lam[cp0 + 1], l2 = lam[cp0 + 2];
                float l3 = lam[cp0 + 3], l4 = lam[cp0 + 4], l5 = lam[cp0 + 5];
                float l6 = lam[cp0 + 6];
                float l7 = lam[cq0 + 0], l8 = lam[cq0 + 1], l9 = lam[cq0 + 2];
                float l10 = lam[cq0 + 3], l11 = lam[cq0 + 4], l12 = lam[cq0 + 5];
                float l13 = lam[cq0 + 6];
                if (r == 0) {
                    INTRA_MR(1, 6, 2, 5, 3, 4, 8, 13, 9, 12, 10, 11);
                    INTRA_MR(0, 1, 2, 6, 3, 5, 7, 8, 9, 13, 10, 12);
                    INTRA_MR(0, 2, 3, 6, 4, 5, 7, 9, 10, 13, 11, 12);
                    INTRA_MR(0, 3, 1, 2, 4, 6, 7, 10, 8, 9, 11, 13);
                    INTRA_MR(0, 4, 1, 3, 5, 6, 7, 11, 8, 10, 12, 13);
                    INTRA_MR(0, 5, 1, 4, 2, 3, 7, 12, 8, 11, 9, 10);
                    INTRA_MR(0, 6, 1, 5, 2, 4, 7, 13, 8, 12, 9, 11);
                }
                CROSS_MR(7, 8, 9, 10, 11, 12, 13);
                CROSS_MR(8, 9, 10, 11, 12, 13, 7);
                CROSS_MR(9, 10, 11, 12, 13, 7, 8);
                CROSS_MR(10, 11, 12, 13, 7, 8, 9);
                CROSS_MR(11, 12, 13, 7, 8, 9, 10);
                CROSS_MR(12, 13, 7, 8, 9, 10, 11);
                CROSS_MR(13, 7, 8, 9, 10, 11, 12);
                colp[0 * 64] = c0; colp[1 * 64] = c1; colp[2 * 64] = c2;
                colp[3 * 64] = c3; colp[4 * 64] = c4; colp[5 * 64] = c5;
                colp[6 * 64] = c6;
                colq[0 * 64] = c7; colq[1 * 64] = c8; colq[2 * 64] = c9;
                colq[3 * 64] = c10; colq[4 * 64] = c11; colq[5 * 64] = c12;
                colq[6 * 64] = c13;
                if (lane == 0) {
                    lam[cp0 + 0] = l0; lam[cp0 + 1] = l1; lam[cp0 + 2] = l2;
                    lam[cp0 + 3] = l3; lam[cp0 + 4] = l4; lam[cp0 + 5] = l5;
                    lam[cp0 + 6] = l6;
                    lam[cq0 + 0] = l7; lam[cq0 + 1] = l8; lam[cq0 + 2] = l9;
                    lam[cq0 + 3] = l10; lam[cq0 + 4] = l11; lam[cq0 + 5] = l12;
                    lam[cq0 + 6] = l13;
                }
            }
            __syncthreads();
        }
    }
}

// --------------------------------- exact norms + select 45 smallest
__global__ __launch_bounds__(256) void select_kernel(const float* __restrict__ G,
                                                     int* __restrict__ tail_idx,
                                                     float* __restrict__ invl2) {
    int b = blockIdx.x;
    const float* Gb = G + (size_t)b * NH * CSTRIDE;
    __shared__ float lam[NH];
    __shared__ int cnt;
    int tid = threadIdx.x, lane = tid & 63, wid = tid >> 6;  // 4 waves
    if (tid == 0) cnt = 0;
    for (int j = wid * 56; j < wid * 56 + 56; ++j) {
        float4 v = ((const float4*)(Gb + j * CSTRIDE))[lane];
        float d = dot4(v, v);
        d += __shfl_xor(d, 32); d += __shfl_xor(d, 16); d += __shfl_xor(d, 8);
        d += __shfl_xor(d, 4);  d += __shfl_xor(d, 2);  d += __shfl_xor(d, 1);
        if (lane == 0) lam[j] = d;
    }
    __syncthreads();
    if (tid < NH) {
        float my = lam[tid];
        int rank = 0;
        for (int i = 0; i < NH; ++i) {
            float o = lam[i];
            rank += (o > my) ? 1 : ((o == my && i < tid) ? 1 : 0);
        }
        if (rank >= KKEEP) {
            int pos = atomicAdd(&cnt, 1);
            tail_idx[b * NTAIL + pos] = tid;
            invl2[b * NTAIL + pos] = 1.f / my;  // ||col||^2 = lambda^2
        }
    }
}

// ------------------------------- C[b][t][w'] = (col_t^T A)[w'] / lambda^2
__global__ __launch_bounds__(128) void ctail_kernel(const float* __restrict__ G,
                                                    const float* __restrict__ x,
                                                    const int* __restrict__ mask,
                                                    const int* __restrict__ tail_idx,
                                                    const float* __restrict__ invl2,
                                                    float* __restrict__ C) {
    int b = blockIdx.y;
    int wchunk = blockIdx.x;  // 6 chunks of 112
    __shared__ float sT[NTAIL * NH];
    __shared__ float sInv[NTAIL];
    __shared__ int sIdx[NTAIL];
    int tid = threadIdx.x;
    if (tid < NTAIL) {
        sIdx[tid] = tail_idx[b * NTAIL + tid];
        sInv[tid] = invl2[b * NTAIL + tid];
    }
    __syncthreads();
    for (int idx = tid; idx < NTAIL * NH; idx += 128) {
        int t = idx / NH, h = idx - t * NH;
        sT[idx] = G[((size_t)b * NH + sIdx[t]) * CSTRIDE + h];
    }
    __syncthreads();
    if (tid < 112) {
        int wp = wchunk * 112 + tid;
        int c = wp / NH;
        int w = wp - c * NH;
        const float* xb = x + ((size_t)(b * 3 + c) * NH) * NH + w;
        const int* mb = mask + (size_t)b * NH * NCW + wp;
        float acc[NTAIL];
#pragma unroll
        for (int t = 0; t < NTAIL; ++t) acc[t] = 0.f;
        for (int h = 0; h < NH; ++h) {
            float a = mb[h * NCW] ? 2.f * xb[h * NH] - 1.f : 0.f;
#pragma unroll
            for (int t = 0; t < NTAIL; ++t) acc[t] += sT[t * NH + h] * a;
        }
        float* Cb = C + ((size_t)b * NTAIL) * NCW + wp;
#pragma unroll
        for (int t = 0; t < NTAIL; ++t) Cb[t * NCW] = acc[t] * sInv[t];
    }
}

// ----------------------------------------------------------- final output
__global__ __launch_bounds__(256) void out_kernel(const float* __restrict__ G,
                                                  const float* __restrict__ x,
                                                  const int* __restrict__ mask,
                                                  const int* __restrict__ tail_idx,
                                                  const float* __restrict__ C,
                                                  const float* __restrict__ invp,
                                                  float* __restrict__ out) {
    int b = blockIdx.z, hc = blockIdx.y, wc = blockIdx.x;
    int h0 = hc * 32, w0 = wc * 96;
    __shared__ float sCol[NTAIL * 32];
    __shared__ float sC[NTAIL * 96];
    __shared__ int sIdx[NTAIL];
    int tid = threadIdx.x;
    if (tid < NTAIL) sIdx[tid] = tail_idx[b * NTAIL + tid];
    __syncthreads();
    for (int i = tid; i < NTAIL * 32; i += 256) {
        int t = i >> 5, hl = i & 31;
        sCol[i] = G[((size_t)b * NH + sIdx[t]) * CSTRIDE + h0 + hl];
    }
    for (int i = tid; i < NTAIL * 96; i += 256) {
        int t = i / 96, wl = i - t * 96;
        sC[i] = C[((size_t)b * NTAIL + t) * NCW + w0 + wl];
    }
    __syncthreads();
    float ip = invp[b];
    for (int i = tid; i < 32 * 96; i += 256) {
        int hl = i / 96, wl = i - hl * 96;
        int h = h0 + hl, wp = w0 + wl;
        int c = wp / NH, w = wp - c * NH;
        float a = mask[(size_t)b * NH * NCW + h * NCW + wp]
                      ? 2.f * x[((size_t)(b * 3 + c) * NH + h) * NH + w] - 1.f
                      : 0.f;
        float corr = 0.f;
#pragma unroll
        for (int t = 0; t < NTAIL; ++t) corr += sCol[t * 32 + hl] * sC[t * 96 + wl];
        float val = (a - corr) * ip;
        val = fminf(1.f, fmaxf(-1.f, val));
        out[((size_t)(b * 3 + c) * NH + h) * NH + w] = (val + 1.f) * 0.5f;
    }
}

extern "C" void kernel_launch(void* const* d_in, const int* in_sizes, int n_in,
                              void* d_out, int out_size, void* d_ws, size_t ws_size,
                              hipStream_t stream) {
    const float* x = (const float*)d_in[0];
    const int* mask = (const int*)d_in[1];
    float* out = (float*)d_out;
    char* ws = (char*)d_ws;

    const size_t off_G = 0;
    const size_t sz_G = (size_t)BATCH * NH * CSTRIDE * 4;
    const size_t off_invp = off_G + sz_G;
    const size_t off_tail = off_invp + 256;
    const size_t off_invl2 = off_tail + (size_t)BATCH * NTAIL * 4;
    const size_t off_C = off_invl2 + (size_t)BATCH * NTAIL * 4;

    float* G = (float*)(ws + off_G);
    float* invp = (float*)(ws + off_invp);
    int* tail = (int*)(ws + off_tail);
    float* invl2 = (float*)(ws + off_invl2);
    float* C = (float*)(ws + off_C);

    pobs_kernel<<<BATCH, 256, 0, stream>>>(mask, invp);
    pad_kernel<<<(BATCH * NH * 32) / 256, 256, 0, stream>>>(G);
    gram_kernel<<<dim3(49, BATCH), 256, 0, stream>>>(x, mask, G);
    jacobi_kernel<<<BATCH, 512, 0, stream>>>(G);
    select_kernel<<<BATCH, 256, 0, stream>>>(G, tail, invl2);
    ctail_kernel<<<dim3(6, BATCH), 128, 0, stream>>>(G, x, mask, tail, invl2, C);
    out_kernel<<<dim3(7, 7, BATCH), 256, 0, stream>>>(G, x, mask, tail, C, invp, out);
}